// Round 7
// baseline (438.559 us; speedup 1.0000x reference)
//
#include <hip/hip_runtime.h>
#include <hip/hip_bf16.h>

#define LL 4096
#define DD 192
#define NN 16
#define NCH 128     // chunks for the 2-pass scan
#define LC  32      // steps per chunk = LL/NCH

typedef float v2f __attribute__((ext_vector_type(2)));
typedef float f32x4 __attribute__((ext_vector_type(4)));
typedef short bf16x8 __attribute__((ext_vector_type(8)));   // 8 bf16 in 4 VGPRs

__device__ __forceinline__ v2f v2(float a, float b) { v2f r; r.x = a; r.y = b; return r; }
__device__ __forceinline__ float fexp2(float x) { return __builtin_amdgcn_exp2f(x); }

// ---------------------------------------------------------------------------
// SCAN-KERNEL LEDGER (k_scanc dur across variants):
//   R11 no-LDS 54%occ: 99.3 | R12 LDS 33%: 97.6 | R15: 100.6 | R16 poly
//   (+~400 VALU cyc/step): 164.2 | R17 dtr-prefetch: 100.1.
// -> responds 1:1 to instruction count, NOT to occupancy/operand-path/
//    prefetch. R16 LESSON: VALU-issue regime, HW exp2 is cheap - keep it.
// R18 hypothesis: 192-thread (3-wave) blocks misload the 4 SIMDs/CU (up to
// 25% idle, invariant to everything we varied). Fix: 1-wave blocks, d split
// over blockIdx.z.
// ---------------------------------------------------------------------------

// async global->LDS, 16 B per lane, dest = uniform base + lane*16 (HW rule).
// NOTE (R14 post-mortem): R13/R14's 16x FETCH/WRITE explosion was SCRATCH
// traffic from regalloc spills (symmetric fetch+write, dispatch-0 alloc
// stall, VGPR 64->40 drop). Spill watch: WRITE above 49152 KB + slow
// dispatch-0. Keep VGPR headroom in launch_bounds.
#define GLDS16(gp, lp) __builtin_amdgcn_global_load_lds(                      \
    (const __attribute__((address_space(1))) void*)(gp),                      \
    (__attribute__((address_space(3))) void*)(lp), 16, 0, 0)

// ---------------------------------------------------------------------------
// K0: weight repack for the MFMA projection (unchanged).
// ---------------------------------------------------------------------------
__global__ __launch_bounds__(192) void k_wprep(
    const float* __restrict__ Wp, __hip_bfloat16* __restrict__ Whi,
    __hip_bfloat16* __restrict__ Wlo)
{
  const int d = threadIdx.x;
  const int r = blockIdx.x;
  const int k = r / 48, cc = r % 48;
  float v = 0.f;
  if      (cc < 6)               v = Wp[((size_t)k * 38 + cc) * DD + d];
  else if (cc >= 8  && cc < 24)  v = Wp[((size_t)k * 38 + 6  + (cc - 8))  * DD + d];
  else if (cc >= 24 && cc < 40)  v = Wp[((size_t)k * 38 + 22 + (cc - 24)) * DD + d];
  const __hip_bfloat16 hi = __float2bfloat16(v);
  Whi[(size_t)r * DD + d] = hi;
  Wlo[(size_t)r * DD + d] = __float2bfloat16(v - __bfloat162float(hi));
}

// ---------------------------------------------------------------------------
// K0b: A-table precompute. Ant[kd][n] = -exp(Alog)*log2e, fp32 [768][16].
// ---------------------------------------------------------------------------
__global__ __launch_bounds__(256) void k_an(
    const float* __restrict__ Alog, float* __restrict__ Ant)
{
  const int i = blockIdx.x * 256 + threadIdx.x;   // 12288 total
  Ant[i] = -__expf(Alog[i]) * 1.4426950408889634f;
}

// ---------------------------------------------------------------------------
// K2: tiled transpose x[b,d,p] -> xh (bf16 hi) + xl (residual) (unchanged).
// ---------------------------------------------------------------------------
__global__ __launch_bounds__(256) void k_xt(
    const float* __restrict__ x, __hip_bfloat16* __restrict__ xh,
    __hip_bfloat16* __restrict__ xl)
{
  __shared__ float tile[64][65];
  const int b = blockIdx.z, d0 = blockIdx.y * 64, p0 = blockIdx.x * 64;
  const int tx = threadIdx.x & 63, ty = threadIdx.x >> 6;
#pragma unroll
  for (int r = ty; r < 64; r += 4)
    tile[r][tx] = x[((size_t)b * DD + d0 + r) * LL + p0 + tx];
  __syncthreads();
#pragma unroll
  for (int pr = ty; pr < 64; pr += 4) {
    const float vv = tile[tx][pr];
    const __hip_bfloat16 hi = __float2bfloat16(vv);
    const size_t idx = ((size_t)b * LL + p0 + pr) * DD + d0 + tx;
    xh[idx] = hi;
    xl[idx] = __float2bfloat16(vv - __bfloat162float(hi));
  }
}

// ---------------------------------------------------------------------------
// K1: MFMA projection (unchanged).
// ---------------------------------------------------------------------------
__global__ __launch_bounds__(192) void k_mfproj(
    const __hip_bfloat16* __restrict__ xh, const __hip_bfloat16* __restrict__ xl,
    const __hip_bfloat16* __restrict__ Whi, const __hip_bfloat16* __restrict__ Wlo,
    float* __restrict__ dtr, float* __restrict__ Bsv, float* __restrict__ Csv)
{
  const int tid  = threadIdx.x;
  const int w    = tid >> 6;          // wave 0..2
  const int lane = tid & 63;
  const int n    = lane & 15;
  const int quad = lane >> 4;
  const int p0   = blockIdx.x * 16;
  const int b    = blockIdx.y;
  const int p    = p0 + n;

  const short* __restrict__ xhp = (const short*)xh + ((size_t)b * LL + p) * DD + quad * 8;
  const short* __restrict__ xlp = (const short*)xl + ((size_t)b * LL + p) * DD + quad * 8;
  const short* __restrict__ whp = (const short*)Whi + ((size_t)(w * 4) * 16 + n) * DD + quad * 8;
  const short* __restrict__ wlp = (const short*)Wlo + ((size_t)(w * 4) * 16 + n) * DD + quad * 8;

  f32x4 acc[4];
#pragma unroll
  for (int m = 0; m < 4; ++m) acc[m] = (f32x4){0.f, 0.f, 0.f, 0.f};

#pragma unroll
  for (int ks = 0; ks < 6; ++ks) {
    const bf16x8 bh = *(const bf16x8*)(xhp + ks * 32);
    const bf16x8 bl = *(const bf16x8*)(xlp + ks * 32);
#pragma unroll
    for (int m = 0; m < 4; ++m) {
      const bf16x8 ah = *(const bf16x8*)(whp + (size_t)m * 16 * DD + ks * 32);
      const bf16x8 al = *(const bf16x8*)(wlp + (size_t)m * 16 * DD + ks * 32);
      acc[m] = __builtin_amdgcn_mfma_f32_16x16x32_bf16(ah, bh, acc[m], 0, 0, 0);
      acc[m] = __builtin_amdgcn_mfma_f32_16x16x32_bf16(ah, bl, acc[m], 0, 0, 0);
      acc[m] = __builtin_amdgcn_mfma_f32_16x16x32_bf16(al, bh, acc[m], 0, 0, 0);
    }
  }

  const int sg = ((p & 63) << 6) | (p >> 6);     // sigma(p)
  int lsv[4] = { p, sg, LL - 1 - p, LL - 1 - sg };

#pragma unroll
  for (int m = 0; m < 4; ++m) {
    const int mt = w * 4 + m;
    const int k  = mt / 3;                        // direction
    const int t  = mt - k * 3;                    // tile within direction
    const int cc0 = t * 16 + quad * 4;            // packed channel of reg 0
    const size_t rowb = (size_t)(b * 4 + k) * LL + lsv[k];
    const float4 vv = make_float4(acc[m][0], acc[m][1], acc[m][2], acc[m][3]);
    if      (cc0 < 8)  *(float4*)(dtr + rowb * 8  + cc0)        = vv;
    else if (cc0 < 24) *(float4*)(Bsv + rowb * 16 + (cc0 - 8))  = vv;
    else if (cc0 < 40) *(float4*)(Csv + rowb * 16 + (cc0 - 24)) = vv;
  }
}

// u-row index for scan position l of direction k.
__device__ __forceinline__ int urow(int l, bool rev, bool trans) {
  const int rl = rev ? (LL - 1 - l) : l;
  return trans ? (((rl & 63) << 6) | (rl >> 6)) : rl;
}

// ---------------------------------------------------------------------------
// K3 (pass A): per-chunk scan summaries. R18: 1-WAVE blocks (64 threads),
// d split over blockIdx.z (3 groups of 64). Body identical to R17.
// LDS 2 KiB/block.
// ---------------------------------------------------------------------------
__global__ __launch_bounds__(64, 6) void k_partial(
    const float* __restrict__ dtr, const float* __restrict__ Bsv,
    const __hip_bfloat16* __restrict__ xt, const float* __restrict__ Ant,
    const float* __restrict__ dtw, const float* __restrict__ dtb,
    __hip_bfloat16* __restrict__ Pv, __hip_bfloat16* __restrict__ qv)
{
  __shared__ __align__(16) float smem[LC * 16];   // B, one wave's copy
  const int lane = threadIdx.x;
  const int d  = blockIdx.z * 64 + lane;
  const int bk = blockIdx.x;
  const int c  = blockIdx.y;
  const int k = bk & 3, b = bk >> 2;
  const int kd = k * DD + d;
  const bool rev = (k >= 2), trans = (k & 1);
  const int l0 = c * LC;

  float* sB = smem;    // [LC][16]
  {
    const float* gB = Bsv + ((size_t)bk * LL + l0) * NN;   // 2048 B
    GLDS16(gB + lane * 4, sB);
    GLDS16(gB + 256 + lane * 4, sB + 256);
  }

  v2f An2[8];
  {
    const float4* __restrict__ at = (const float4*)(Ant + (size_t)kd * NN);
    const float4 t0 = at[0], t1 = at[1], t2 = at[2], t3 = at[3];
    An2[0]=v2(t0.x,t0.y); An2[1]=v2(t0.z,t0.w);
    An2[2]=v2(t1.x,t1.y); An2[3]=v2(t1.z,t1.w);
    An2[4]=v2(t2.x,t2.y); An2[5]=v2(t2.z,t2.w);
    An2[6]=v2(t3.x,t3.y); An2[7]=v2(t3.z,t3.w);
  }
  const float w0 = dtw[kd*6+0], w1 = dtw[kd*6+1], w2 = dtw[kd*6+2],
              w3 = dtw[kd*6+3], w4 = dtw[kd*6+4], w5 = dtw[kd*6+5];
  const float bias = dtb[kd];
  const ushort* __restrict__ up = (const ushort*)xt + (size_t)b * LL * DD + d;
  const float* __restrict__ dtrp = dtr + (size_t)bk * LL * 8;   // uniform rows

  // 8-deep rolling register prefetch of the per-thread u stream (R12 form).
  uint ucur[8], unext[8] = {0,0,0,0,0,0,0,0};
#pragma unroll
  for (int i = 0; i < 8; ++i)
    ucur[i] = up[(size_t)urow(l0 + i, rev, trans) * DD];

  // depth-1 prefetch of the dtr pair (R17)
  float4 r0c = *(const float4*)(dtrp + (size_t)l0 * 8);
  float2 r1c = *(const float2*)(dtrp + (size_t)l0 * 8 + 4);

  asm volatile("s_waitcnt vmcnt(0)" ::: "memory");   // staged LDS + group-0 u ready

  float spsum = 0.f;
  v2f q2[8];
#pragma unroll
  for (int j = 0; j < 8; ++j) q2[j] = v2(0.f, 0.f);

  for (int g = 0; g < 4; ++g) {
    if (g < 3) {
#pragma unroll
      for (int i = 0; i < 8; ++i)
        unext[i] = up[(size_t)urow(l0 + 8 * g + 8 + i, rev, trans) * DD];
    }
#pragma unroll
    for (int ii = 0; ii < 8; ++ii) {
      const int i = 8 * g + ii;
      const int l = l0 + i;
      const int lp = (i + 1 < LC) ? (l + 1) : l;   // next step's dtr row (clamped)
      const float4 r0n = *(const float4*)(dtrp + (size_t)lp * 8);
      const float2 r1n = *(const float2*)(dtrp + (size_t)lp * 8 + 4);
      const float uc = __uint_as_float(ucur[ii] << 16);
      const float4 B0 = *(const float4*)(sB + i * 16);
      const float4 B1 = *(const float4*)(sB + i * 16 + 4);
      const float4 B2 = *(const float4*)(sB + i * 16 + 8);
      const float4 B3 = *(const float4*)(sB + i * 16 + 12);
      float v = bias + r0c.x*w0 + r0c.y*w1 + r0c.z*w2 + r0c.w*w3 + r1c.x*w4 + r1c.y*w5;
      const float sp = (v > 20.f) ? v : __logf(1.f + __expf(v));
      const float dbu = sp * uc;
      spsum += sp;
      const v2f sp2  = v2(sp, sp);
      const v2f dbu2 = v2(dbu, dbu);
      const v2f Bv[8] = { v2(B0.x,B0.y), v2(B0.z,B0.w), v2(B1.x,B1.y), v2(B1.z,B1.w),
                          v2(B2.x,B2.y), v2(B2.z,B2.w), v2(B3.x,B3.y), v2(B3.z,B3.w) };
#pragma unroll
      for (int j = 0; j < 8; ++j) {
        const v2f a = sp2 * An2[j];                 // v_pk_mul
        v2f e; e.x = fexp2(a.x); e.y = fexp2(a.y);
        q2[j] = __builtin_elementwise_fma(q2[j], e, dbu2 * Bv[j]);  // pk_mul+pk_fma
      }
      r0c = r0n; r1c = r1n;
    }
#pragma unroll
    for (int i = 0; i < 8; ++i) ucur[i] = unext[i];
  }

  __hip_bfloat16* __restrict__ Pp = Pv + (((size_t)bk * NCH + c) * DD + d) * NN;
  __hip_bfloat16* __restrict__ qp = qv + (((size_t)bk * NCH + c) * DD + d) * NN;
#pragma unroll
  for (int j = 0; j < 8; ++j) {
    Pp[2*j]   = __float2bfloat16(fexp2(An2[j].x * spsum));
    Pp[2*j+1] = __float2bfloat16(fexp2(An2[j].y * spsum));
    qp[2*j]   = __float2bfloat16(q2[j].x);
    qp[2*j+1] = __float2bfloat16(q2[j].y);
  }
}

// ---------------------------------------------------------------------------
// K4 (pass B): combine chunk summaries; h_in[c] overwrites P[c] in place.
// ---------------------------------------------------------------------------
__global__ __launch_bounds__(256) void k_comb(
    __hip_bfloat16* __restrict__ Pv, const __hip_bfloat16* __restrict__ qv)
{
  const int idx = blockIdx.x * 256 + threadIdx.x;
  const int dn = idx % (DD * NN);
  const int bk = idx / (DD * NN);
  const size_t base = (size_t)bk * NCH * DD * NN + dn;
  float h = 0.f;
  for (int c = 0; c < NCH; ++c) {
    const size_t a = base + (size_t)c * DD * NN;
    const float Pc = __bfloat162float(Pv[a]);
    const float qc = __bfloat162float(qv[a]);
    Pv[a] = __float2bfloat16(h);          // hin[c] = h (pre-chunk state)
    h = fmaf(Pc, h, qc);
  }
}

// ---------------------------------------------------------------------------
// K5 (pass C): real scan per chunk seeded with h_in. R18: 1-wave blocks,
// d split over blockIdx.z. Body identical to R17. LDS 4 KiB/block.
// ---------------------------------------------------------------------------
__global__ __launch_bounds__(64, 6) void k_scanc(
    const float* __restrict__ dtr, const float* __restrict__ Bsv,
    const float* __restrict__ Csv, const __hip_bfloat16* __restrict__ xt,
    const float* __restrict__ Ant,
    const float* __restrict__ dtw, const float* __restrict__ dtb,
    const __hip_bfloat16* __restrict__ hin, __hip_bfloat16* __restrict__ ys)
{
  __shared__ __align__(16) float smem[LC * 32];   // B + C, one wave's copy
  const int lane = threadIdx.x;
  const int d  = blockIdx.z * 64 + lane;
  const int bk = blockIdx.x;
  const int c  = blockIdx.y;
  const int k = bk & 3, b = bk >> 2;
  const int kd = k * DD + d;
  const bool rev = (k >= 2), trans = (k & 1);
  const int l0 = c * LC;

  float* sB = smem;             // [LC][16]
  float* sC = smem + LC * 16;   // [LC][16]
  {
    const float* gB = Bsv + ((size_t)bk * LL + l0) * NN;   // 2048 B
    const float* gC = Csv + ((size_t)bk * LL + l0) * NN;   // 2048 B
    GLDS16(gB + lane * 4, sB);
    GLDS16(gB + 256 + lane * 4, sB + 256);
    GLDS16(gC + lane * 4, sC);
    GLDS16(gC + 256 + lane * 4, sC + 256);
  }

  v2f An2[8];
  {
    const float4* __restrict__ at = (const float4*)(Ant + (size_t)kd * NN);
    const float4 t0 = at[0], t1 = at[1], t2 = at[2], t3 = at[3];
    An2[0]=v2(t0.x,t0.y); An2[1]=v2(t0.z,t0.w);
    An2[2]=v2(t1.x,t1.y); An2[3]=v2(t1.z,t1.w);
    An2[4]=v2(t2.x,t2.y); An2[5]=v2(t2.z,t2.w);
    An2[6]=v2(t3.x,t3.y); An2[7]=v2(t3.z,t3.w);
  }
  const float w0 = dtw[kd*6+0], w1 = dtw[kd*6+1], w2 = dtw[kd*6+2],
              w3 = dtw[kd*6+3], w4 = dtw[kd*6+4], w5 = dtw[kd*6+5];
  const float bias = dtb[kd];
  const ushort* __restrict__ up = (const ushort*)xt + (size_t)b * LL * DD + d;
  const float* __restrict__ dtrp = dtr + (size_t)bk * LL * 8;   // uniform rows
  __hip_bfloat16* __restrict__ yp = ys + (size_t)bk * LL * DD + d;

  v2f h2[8];
  const __hip_bfloat16* __restrict__ hp = hin + (((size_t)bk * NCH + c) * DD + d) * NN;
#pragma unroll
  for (int j = 0; j < 8; ++j)
    h2[j] = v2(__bfloat162float(hp[2*j]), __bfloat162float(hp[2*j+1]));

  uint ucur[8], unext[8] = {0,0,0,0,0,0,0,0};
#pragma unroll
  for (int i = 0; i < 8; ++i)
    ucur[i] = up[(size_t)urow(l0 + i, rev, trans) * DD];

  // depth-1 prefetch of the dtr pair (R17)
  float4 r0c = *(const float4*)(dtrp + (size_t)l0 * 8);
  float2 r1c = *(const float2*)(dtrp + (size_t)l0 * 8 + 4);

  asm volatile("s_waitcnt vmcnt(0)" ::: "memory");   // staged LDS + group-0 u ready

  for (int g = 0; g < 4; ++g) {
    if (g < 3) {
#pragma unroll
      for (int i = 0; i < 8; ++i)
        unext[i] = up[(size_t)urow(l0 + 8 * g + 8 + i, rev, trans) * DD];
    }
#pragma unroll
    for (int ii = 0; ii < 8; ++ii) {
      const int i = 8 * g + ii;
      const int l = l0 + i;
      const int lp = (i + 1 < LC) ? (l + 1) : l;   // next step's dtr row (clamped)
      const float4 r0n = *(const float4*)(dtrp + (size_t)lp * 8);
      const float2 r1n = *(const float2*)(dtrp + (size_t)lp * 8 + 4);
      const int rowc = urow(l, rev, trans);
      const float uc = __uint_as_float(ucur[ii] << 16);
      const float4 B0 = *(const float4*)(sB + i * 16);
      const float4 B1 = *(const float4*)(sB + i * 16 + 4);
      const float4 B2 = *(const float4*)(sB + i * 16 + 8);
      const float4 B3 = *(const float4*)(sB + i * 16 + 12);
      const float4 C0 = *(const float4*)(sC + i * 16);
      const float4 C1 = *(const float4*)(sC + i * 16 + 4);
      const float4 C2 = *(const float4*)(sC + i * 16 + 8);
      const float4 C3 = *(const float4*)(sC + i * 16 + 12);
      float v = bias + r0c.x*w0 + r0c.y*w1 + r0c.z*w2 + r0c.w*w3 + r1c.x*w4 + r1c.y*w5;
      const float sp = (v > 20.f) ? v : __logf(1.f + __expf(v));
      const float dbu = sp * uc;
      const v2f sp2  = v2(sp, sp);
      const v2f dbu2 = v2(dbu, dbu);
      const v2f Bv[8] = { v2(B0.x,B0.y), v2(B0.z,B0.w), v2(B1.x,B1.y), v2(B1.z,B1.w),
                          v2(B2.x,B2.y), v2(B2.z,B2.w), v2(B3.x,B3.y), v2(B3.z,B3.w) };
      const v2f Cv[8] = { v2(C0.x,C0.y), v2(C0.z,C0.w), v2(C1.x,C1.y), v2(C1.z,C1.w),
                          v2(C2.x,C2.y), v2(C2.z,C2.w), v2(C3.x,C3.y), v2(C3.z,C3.w) };
      v2f ya = v2(0.f, 0.f), yb = v2(0.f, 0.f), yc = v2(0.f, 0.f), yd = v2(0.f, 0.f);
#pragma unroll
      for (int j = 0; j < 8; ++j) {
        const v2f a = sp2 * An2[j];
        v2f e; e.x = fexp2(a.x); e.y = fexp2(a.y);
        h2[j] = __builtin_elementwise_fma(h2[j], e, dbu2 * Bv[j]);
        v2f& yacc = (j < 2) ? ya : (j < 4) ? yb : (j < 6) ? yc : yd;
        yacc = __builtin_elementwise_fma(h2[j], Cv[j], yacc);
      }
      const v2f ysum = (ya + yb) + (yc + yd);
      yp[(size_t)rowc * DD] = __float2bfloat16(ysum.x + ysum.y);
      r0c = r0n; r1c = r1n;
    }
#pragma unroll
    for (int i = 0; i < 8; ++i) ucur[i] = unext[i];
  }
}

// ---------------------------------------------------------------------------
// K6: merge + D-skip + LayerNorm(192) + channel-last store (unchanged).
// ---------------------------------------------------------------------------
__global__ __launch_bounds__(64) void k_merge(
    const __hip_bfloat16* __restrict__ ys,
    const __hip_bfloat16* __restrict__ xh, const __hip_bfloat16* __restrict__ xl,
    const float* __restrict__ Ds, const float* __restrict__ nw,
    const float* __restrict__ nb, float* __restrict__ out)
{
  const int lane = threadIdx.x;
  const int b = blockIdx.y;
  const int q0 = blockIdx.x * 8;

  float Dsum[3], nwv[3], nbv[3];
#pragma unroll
  for (int i = 0; i < 3; ++i) {
    int d = lane + 64 * i;
    Dsum[i] = Ds[d] + Ds[DD + d] + Ds[2 * DD + d] + Ds[3 * DD + d];
    nwv[i] = nw[d];
    nbv[i] = nb[d];
  }
  const __hip_bfloat16* __restrict__ ysb = ys + (size_t)b * 4 * LL * DD;
  const __hip_bfloat16* __restrict__ xhb = xh + (size_t)b * LL * DD;
  const __hip_bfloat16* __restrict__ xlb = xl + (size_t)b * LL * DD;
  float* __restrict__ ob = out + (size_t)b * LL * DD;

  float v[8][3];
#pragma unroll
  for (int j = 0; j < 8; ++j) {
    const int pos = q0 + j;
#pragma unroll
    for (int i = 0; i < 3; ++i) {
      const int d = lane + 64 * i;
      const size_t idx = (size_t)pos * DD + d;
      float s = __bfloat162float(ysb[idx])
              + __bfloat162float(ysb[(size_t)LL * DD + idx])
              + __bfloat162float(ysb[(size_t)2 * LL * DD + idx])
              + __bfloat162float(ysb[(size_t)3 * LL * DD + idx]);
      const float xv = __bfloat162float(xhb[idx]) + __bfloat162float(xlb[idx]);
      v[j][i] = s + xv * Dsum[i];
    }
  }
#pragma unroll
  for (int j = 0; j < 8; ++j) {
    float s1 = v[j][0] + v[j][1] + v[j][2];
    float s2 = v[j][0]*v[j][0] + v[j][1]*v[j][1] + v[j][2]*v[j][2];
#pragma unroll
    for (int m = 1; m < 64; m <<= 1) {
      s1 += __shfl_xor(s1, m);
      s2 += __shfl_xor(s2, m);
    }
    const float mu  = s1 * (1.f / 192.f);
    const float var = s2 * (1.f / 192.f) - mu * mu;
    const float rs  = rsqrtf(var + 1e-5f);
    const int pos = q0 + j;
#pragma unroll
    for (int i = 0; i < 3; ++i) {
      ob[(size_t)pos * DD + lane + 64 * i] = (v[j][i] - mu) * rs * nwv[i] + nbv[i];
    }
  }
}

// ---------------------------------------------------------------------------
// Workspace (fp32 slots), total 30,458,240 slots = 121.8 MB (unchanged):
//   dtr [32][4096][8]    fp32 @ 0           (1,048,576)
//   Bs  [32][4096][16]   fp32 @ 1,048,576   (2,097,152)
//   Cs  [32][4096][16]   fp32 @ 3,145,728   (2,097,152)
//   xh  [8][4096][192]   bf16 @ 5,242,880   (3,145,728 slots)
//   ys  [32][4096][192]  bf16 @ 8,388,608   (12,582,912 slots)
//     q  [32][128][192][16] bf16 @ 11,534,336 (aliases ys; dead after k_comb)
//   P/hin [32][128][192][16] bf16 @ 20,971,520 (6,291,456 slots)
//   Whi [192][192]       bf16 @ 27,262,976  (18,432 slots)
//   Wlo [192][192]       bf16 @ 27,281,408  (18,432 slots)
//   xl  [8][4096][192]   bf16 @ 27,299,840  (3,145,728 slots)
//   Ant [768][16]        fp32 @ 30,445,568  (12,288 slots)
// ---------------------------------------------------------------------------
extern "C" void kernel_launch(void* const* d_in, const int* in_sizes, int n_in,
                              void* d_out, int out_size, void* d_ws, size_t ws_size,
                              hipStream_t stream)
{
  (void)in_sizes; (void)n_in; (void)out_size; (void)ws_size;
  const float* x    = (const float*)d_in[0];
  const float* Wp   = (const float*)d_in[1];
  const float* dtw  = (const float*)d_in[2];
  const float* dtb  = (const float*)d_in[3];
  const float* Alog = (const float*)d_in[4];
  const float* Ds   = (const float*)d_in[5];
  const float* nw   = (const float*)d_in[6];
  const float* nb   = (const float*)d_in[7];
  float* out = (float*)d_out;
  float* ws  = (float*)d_ws;

  float* dtrw = ws;
  float* Bsv  = ws + 1048576;
  float* Csv  = ws + 3145728;
  __hip_bfloat16* xh  = (__hip_bfloat16*)(ws + 5242880);
  __hip_bfloat16* ysv = (__hip_bfloat16*)(ws + 8388608);
  __hip_bfloat16* qv  = (__hip_bfloat16*)(ws + 11534336);   // alias (dead early)
  __hip_bfloat16* Pv  = (__hip_bfloat16*)(ws + 20971520);
  __hip_bfloat16* Whi = (__hip_bfloat16*)(ws + 27262976);
  __hip_bfloat16* Wlo = (__hip_bfloat16*)(ws + 27281408);
  __hip_bfloat16* xlv = (__hip_bfloat16*)(ws + 27299840);
  float* Ant          = ws + 30445568;

  k_wprep  <<<192, 192, 0, stream>>>(Wp, Whi, Wlo);
  k_an     <<<48, 256, 0, stream>>>(Alog, Ant);
  k_xt     <<<dim3(64, 3, 8), 256, 0, stream>>>(x, xh, xlv);
  k_mfproj <<<dim3(256, 8), 192, 0, stream>>>(xh, xlv, Whi, Wlo, dtrw, Bsv, Csv);
  k_partial<<<dim3(32, NCH, 3), 64, 0, stream>>>(dtrw, Bsv, xh, Ant, dtw, dtb, Pv, qv);
  k_comb   <<<384, 256, 0, stream>>>(Pv, qv);
  k_scanc  <<<dim3(32, NCH, 3), 64, 0, stream>>>(dtrw, Bsv, Csv, xh, Ant, dtw, dtb, Pv, ysv);
  k_merge  <<<dim3(512, 8), 64, 0, stream>>>(ysv, xh, xlv, Ds, nw, nb, out);
}

// Round 8
// 323.935 us; speedup vs baseline: 1.3538x; 1.3538x over previous
//
#include <hip/hip_runtime.h>
#include <hip/hip_bf16.h>

#define LL 4096
#define DD 192
#define NN 16
#define NCH 128     // chunks for the 2-pass scan
#define LC  32      // steps per chunk = LL/NCH

typedef float v2f __attribute__((ext_vector_type(2)));
typedef float f32x4 __attribute__((ext_vector_type(4)));
typedef short bf16x8 __attribute__((ext_vector_type(8)));   // 8 bf16 in 4 VGPRs

__device__ __forceinline__ v2f v2(float a, float b) { v2f r; r.x = a; r.y = b; return r; }
__device__ __forceinline__ float fexp2(float x) { return __builtin_amdgcn_exp2f(x); }

// ---------------------------------------------------------------------------
// SCAN-KERNEL LEDGER (k_scanc dur):
//   R11 no-LDS 54%occ: 99.3 | R12 LDS 33%: 97.6 | R15: 100.6 | R16 poly
//   (+~400 VALU cyc/step): 164.2 | R17 dtr-prefetch: 100.1 | R18 1-wave
//   (64,6): 204 -- SPILLED, test invalid.
// LESSONS:
//  * VALU-issue regime: dur tracks instruction count 1:1 (R16). HW exp2.
//  * SPILL RULE: __launch_bounds__ min-waves>=6 forces the <=64-VGPR bin
//    (per-SIMD pool ~512, coarse quantum) -> this ~70-VGPR body spills to
//    scratch (VGPR reads 40, FETCH/WRITE explode, sym. fetch+write).
//    min-waves=4 is proven clean (R12/R15/R17). NEVER use 6 here.
//  * Spill watch: WRITE must be exactly 49152 KB, VGPR ~64-70.
// R19: retry 1-wave blocks with (64,4) -- valid SIMD-balance test.
// ---------------------------------------------------------------------------

// async global->LDS, 16 B per lane, dest = uniform base + lane*16 (HW rule).
#define GLDS16(gp, lp) __builtin_amdgcn_global_load_lds(                      \
    (const __attribute__((address_space(1))) void*)(gp),                      \
    (__attribute__((address_space(3))) void*)(lp), 16, 0, 0)

// ---------------------------------------------------------------------------
// K0: weight repack for the MFMA projection (unchanged).
// ---------------------------------------------------------------------------
__global__ __launch_bounds__(192) void k_wprep(
    const float* __restrict__ Wp, __hip_bfloat16* __restrict__ Whi,
    __hip_bfloat16* __restrict__ Wlo)
{
  const int d = threadIdx.x;
  const int r = blockIdx.x;
  const int k = r / 48, cc = r % 48;
  float v = 0.f;
  if      (cc < 6)               v = Wp[((size_t)k * 38 + cc) * DD + d];
  else if (cc >= 8  && cc < 24)  v = Wp[((size_t)k * 38 + 6  + (cc - 8))  * DD + d];
  else if (cc >= 24 && cc < 40)  v = Wp[((size_t)k * 38 + 22 + (cc - 24)) * DD + d];
  const __hip_bfloat16 hi = __float2bfloat16(v);
  Whi[(size_t)r * DD + d] = hi;
  Wlo[(size_t)r * DD + d] = __float2bfloat16(v - __bfloat162float(hi));
}

// ---------------------------------------------------------------------------
// K0b: A-table precompute. Ant[kd][n] = -exp(Alog)*log2e, fp32 [768][16].
// ---------------------------------------------------------------------------
__global__ __launch_bounds__(256) void k_an(
    const float* __restrict__ Alog, float* __restrict__ Ant)
{
  const int i = blockIdx.x * 256 + threadIdx.x;   // 12288 total
  Ant[i] = -__expf(Alog[i]) * 1.4426950408889634f;
}

// ---------------------------------------------------------------------------
// K2: tiled transpose x[b,d,p] -> xh (bf16 hi) + xl (residual) (unchanged).
// ---------------------------------------------------------------------------
__global__ __launch_bounds__(256) void k_xt(
    const float* __restrict__ x, __hip_bfloat16* __restrict__ xh,
    __hip_bfloat16* __restrict__ xl)
{
  __shared__ float tile[64][65];
  const int b = blockIdx.z, d0 = blockIdx.y * 64, p0 = blockIdx.x * 64;
  const int tx = threadIdx.x & 63, ty = threadIdx.x >> 6;
#pragma unroll
  for (int r = ty; r < 64; r += 4)
    tile[r][tx] = x[((size_t)b * DD + d0 + r) * LL + p0 + tx];
  __syncthreads();
#pragma unroll
  for (int pr = ty; pr < 64; pr += 4) {
    const float vv = tile[tx][pr];
    const __hip_bfloat16 hi = __float2bfloat16(vv);
    const size_t idx = ((size_t)b * LL + p0 + pr) * DD + d0 + tx;
    xh[idx] = hi;
    xl[idx] = __float2bfloat16(vv - __bfloat162float(hi));
  }
}

// ---------------------------------------------------------------------------
// K1: MFMA projection (unchanged).
// ---------------------------------------------------------------------------
__global__ __launch_bounds__(192) void k_mfproj(
    const __hip_bfloat16* __restrict__ xh, const __hip_bfloat16* __restrict__ xl,
    const __hip_bfloat16* __restrict__ Whi, const __hip_bfloat16* __restrict__ Wlo,
    float* __restrict__ dtr, float* __restrict__ Bsv, float* __restrict__ Csv)
{
  const int tid  = threadIdx.x;
  const int w    = tid >> 6;          // wave 0..2
  const int lane = tid & 63;
  const int n    = lane & 15;
  const int quad = lane >> 4;
  const int p0   = blockIdx.x * 16;
  const int b    = blockIdx.y;
  const int p    = p0 + n;

  const short* __restrict__ xhp = (const short*)xh + ((size_t)b * LL + p) * DD + quad * 8;
  const short* __restrict__ xlp = (const short*)xl + ((size_t)b * LL + p) * DD + quad * 8;
  const short* __restrict__ whp = (const short*)Whi + ((size_t)(w * 4) * 16 + n) * DD + quad * 8;
  const short* __restrict__ wlp = (const short*)Wlo + ((size_t)(w * 4) * 16 + n) * DD + quad * 8;

  f32x4 acc[4];
#pragma unroll
  for (int m = 0; m < 4; ++m) acc[m] = (f32x4){0.f, 0.f, 0.f, 0.f};

#pragma unroll
  for (int ks = 0; ks < 6; ++ks) {
    const bf16x8 bh = *(const bf16x8*)(xhp + ks * 32);
    const bf16x8 bl = *(const bf16x8*)(xlp + ks * 32);
#pragma unroll
    for (int m = 0; m < 4; ++m) {
      const bf16x8 ah = *(const bf16x8*)(whp + (size_t)m * 16 * DD + ks * 32);
      const bf16x8 al = *(const bf16x8*)(wlp + (size_t)m * 16 * DD + ks * 32);
      acc[m] = __builtin_amdgcn_mfma_f32_16x16x32_bf16(ah, bh, acc[m], 0, 0, 0);
      acc[m] = __builtin_amdgcn_mfma_f32_16x16x32_bf16(ah, bl, acc[m], 0, 0, 0);
      acc[m] = __builtin_amdgcn_mfma_f32_16x16x32_bf16(al, bh, acc[m], 0, 0, 0);
    }
  }

  const int sg = ((p & 63) << 6) | (p >> 6);     // sigma(p)
  int lsv[4] = { p, sg, LL - 1 - p, LL - 1 - sg };

#pragma unroll
  for (int m = 0; m < 4; ++m) {
    const int mt = w * 4 + m;
    const int k  = mt / 3;                        // direction
    const int t  = mt - k * 3;                    // tile within direction
    const int cc0 = t * 16 + quad * 4;            // packed channel of reg 0
    const size_t rowb = (size_t)(b * 4 + k) * LL + lsv[k];
    const float4 vv = make_float4(acc[m][0], acc[m][1], acc[m][2], acc[m][3]);
    if      (cc0 < 8)  *(float4*)(dtr + rowb * 8  + cc0)        = vv;
    else if (cc0 < 24) *(float4*)(Bsv + rowb * 16 + (cc0 - 8))  = vv;
    else if (cc0 < 40) *(float4*)(Csv + rowb * 16 + (cc0 - 24)) = vv;
  }
}

// u-row index for scan position l of direction k.
__device__ __forceinline__ int urow(int l, bool rev, bool trans) {
  const int rl = rev ? (LL - 1 - l) : l;
  return trans ? (((rl & 63) << 6) | (rl >> 6)) : rl;
}

// ---------------------------------------------------------------------------
// K3 (pass A): per-chunk scan summaries. R19: 1-wave blocks (64 threads),
// d split over blockIdx.z, __launch_bounds__(64,4) (spill-safe cap 128).
// Body identical to R17. LDS 2 KiB/block.
// ---------------------------------------------------------------------------
__global__ __launch_bounds__(64, 4) void k_partial(
    const float* __restrict__ dtr, const float* __restrict__ Bsv,
    const __hip_bfloat16* __restrict__ xt, const float* __restrict__ Ant,
    const float* __restrict__ dtw, const float* __restrict__ dtb,
    __hip_bfloat16* __restrict__ Pv, __hip_bfloat16* __restrict__ qv)
{
  __shared__ __align__(16) float smem[LC * 16];   // B, one wave's copy
  const int lane = threadIdx.x;
  const int d  = blockIdx.z * 64 + lane;
  const int bk = blockIdx.x;
  const int c  = blockIdx.y;
  const int k = bk & 3, b = bk >> 2;
  const int kd = k * DD + d;
  const bool rev = (k >= 2), trans = (k & 1);
  const int l0 = c * LC;

  float* sB = smem;    // [LC][16]
  {
    const float* gB = Bsv + ((size_t)bk * LL + l0) * NN;   // 2048 B
    GLDS16(gB + lane * 4, sB);
    GLDS16(gB + 256 + lane * 4, sB + 256);
  }

  v2f An2[8];
  {
    const float4* __restrict__ at = (const float4*)(Ant + (size_t)kd * NN);
    const float4 t0 = at[0], t1 = at[1], t2 = at[2], t3 = at[3];
    An2[0]=v2(t0.x,t0.y); An2[1]=v2(t0.z,t0.w);
    An2[2]=v2(t1.x,t1.y); An2[3]=v2(t1.z,t1.w);
    An2[4]=v2(t2.x,t2.y); An2[5]=v2(t2.z,t2.w);
    An2[6]=v2(t3.x,t3.y); An2[7]=v2(t3.z,t3.w);
  }
  const float w0 = dtw[kd*6+0], w1 = dtw[kd*6+1], w2 = dtw[kd*6+2],
              w3 = dtw[kd*6+3], w4 = dtw[kd*6+4], w5 = dtw[kd*6+5];
  const float bias = dtb[kd];
  const ushort* __restrict__ up = (const ushort*)xt + (size_t)b * LL * DD + d;
  const float* __restrict__ dtrp = dtr + (size_t)bk * LL * 8;   // uniform rows

  // 8-deep rolling register prefetch of the per-thread u stream (R12 form).
  uint ucur[8], unext[8] = {0,0,0,0,0,0,0,0};
#pragma unroll
  for (int i = 0; i < 8; ++i)
    ucur[i] = up[(size_t)urow(l0 + i, rev, trans) * DD];

  // depth-1 prefetch of the dtr pair (R17)
  float4 r0c = *(const float4*)(dtrp + (size_t)l0 * 8);
  float2 r1c = *(const float2*)(dtrp + (size_t)l0 * 8 + 4);

  asm volatile("s_waitcnt vmcnt(0)" ::: "memory");   // staged LDS + group-0 u ready

  float spsum = 0.f;
  v2f q2[8];
#pragma unroll
  for (int j = 0; j < 8; ++j) q2[j] = v2(0.f, 0.f);

  for (int g = 0; g < 4; ++g) {
    if (g < 3) {
#pragma unroll
      for (int i = 0; i < 8; ++i)
        unext[i] = up[(size_t)urow(l0 + 8 * g + 8 + i, rev, trans) * DD];
    }
#pragma unroll
    for (int ii = 0; ii < 8; ++ii) {
      const int i = 8 * g + ii;
      const int l = l0 + i;
      const int lp = (i + 1 < LC) ? (l + 1) : l;   // next step's dtr row (clamped)
      const float4 r0n = *(const float4*)(dtrp + (size_t)lp * 8);
      const float2 r1n = *(const float2*)(dtrp + (size_t)lp * 8 + 4);
      const float uc = __uint_as_float(ucur[ii] << 16);
      const float4 B0 = *(const float4*)(sB + i * 16);
      const float4 B1 = *(const float4*)(sB + i * 16 + 4);
      const float4 B2 = *(const float4*)(sB + i * 16 + 8);
      const float4 B3 = *(const float4*)(sB + i * 16 + 12);
      float v = bias + r0c.x*w0 + r0c.y*w1 + r0c.z*w2 + r0c.w*w3 + r1c.x*w4 + r1c.y*w5;
      const float sp = (v > 20.f) ? v : __logf(1.f + __expf(v));
      const float dbu = sp * uc;
      spsum += sp;
      const v2f sp2  = v2(sp, sp);
      const v2f dbu2 = v2(dbu, dbu);
      const v2f Bv[8] = { v2(B0.x,B0.y), v2(B0.z,B0.w), v2(B1.x,B1.y), v2(B1.z,B1.w),
                          v2(B2.x,B2.y), v2(B2.z,B2.w), v2(B3.x,B3.y), v2(B3.z,B3.w) };
#pragma unroll
      for (int j = 0; j < 8; ++j) {
        const v2f a = sp2 * An2[j];                 // v_pk_mul
        v2f e; e.x = fexp2(a.x); e.y = fexp2(a.y);
        q2[j] = __builtin_elementwise_fma(q2[j], e, dbu2 * Bv[j]);  // pk_mul+pk_fma
      }
      r0c = r0n; r1c = r1n;
    }
#pragma unroll
    for (int i = 0; i < 8; ++i) ucur[i] = unext[i];
  }

  __hip_bfloat16* __restrict__ Pp = Pv + (((size_t)bk * NCH + c) * DD + d) * NN;
  __hip_bfloat16* __restrict__ qp = qv + (((size_t)bk * NCH + c) * DD + d) * NN;
#pragma unroll
  for (int j = 0; j < 8; ++j) {
    Pp[2*j]   = __float2bfloat16(fexp2(An2[j].x * spsum));
    Pp[2*j+1] = __float2bfloat16(fexp2(An2[j].y * spsum));
    qp[2*j]   = __float2bfloat16(q2[j].x);
    qp[2*j+1] = __float2bfloat16(q2[j].y);
  }
}

// ---------------------------------------------------------------------------
// K4 (pass B): combine chunk summaries; h_in[c] overwrites P[c] in place.
// ---------------------------------------------------------------------------
__global__ __launch_bounds__(256) void k_comb(
    __hip_bfloat16* __restrict__ Pv, const __hip_bfloat16* __restrict__ qv)
{
  const int idx = blockIdx.x * 256 + threadIdx.x;
  const int dn = idx % (DD * NN);
  const int bk = idx / (DD * NN);
  const size_t base = (size_t)bk * NCH * DD * NN + dn;
  float h = 0.f;
  for (int c = 0; c < NCH; ++c) {
    const size_t a = base + (size_t)c * DD * NN;
    const float Pc = __bfloat162float(Pv[a]);
    const float qc = __bfloat162float(qv[a]);
    Pv[a] = __float2bfloat16(h);          // hin[c] = h (pre-chunk state)
    h = fmaf(Pc, h, qc);
  }
}

// ---------------------------------------------------------------------------
// K5 (pass C): real scan per chunk seeded with h_in. R19: 1-wave blocks,
// (64,4). Body identical to R17. LDS 4 KiB/block.
// ---------------------------------------------------------------------------
__global__ __launch_bounds__(64, 4) void k_scanc(
    const float* __restrict__ dtr, const float* __restrict__ Bsv,
    const float* __restrict__ Csv, const __hip_bfloat16* __restrict__ xt,
    const float* __restrict__ Ant,
    const float* __restrict__ dtw, const float* __restrict__ dtb,
    const __hip_bfloat16* __restrict__ hin, __hip_bfloat16* __restrict__ ys)
{
  __shared__ __align__(16) float smem[LC * 32];   // B + C, one wave's copy
  const int lane = threadIdx.x;
  const int d  = blockIdx.z * 64 + lane;
  const int bk = blockIdx.x;
  const int c  = blockIdx.y;
  const int k = bk & 3, b = bk >> 2;
  const int kd = k * DD + d;
  const bool rev = (k >= 2), trans = (k & 1);
  const int l0 = c * LC;

  float* sB = smem;             // [LC][16]
  float* sC = smem + LC * 16;   // [LC][16]
  {
    const float* gB = Bsv + ((size_t)bk * LL + l0) * NN;   // 2048 B
    const float* gC = Csv + ((size_t)bk * LL + l0) * NN;   // 2048 B
    GLDS16(gB + lane * 4, sB);
    GLDS16(gB + 256 + lane * 4, sB + 256);
    GLDS16(gC + lane * 4, sC);
    GLDS16(gC + 256 + lane * 4, sC + 256);
  }

  v2f An2[8];
  {
    const float4* __restrict__ at = (const float4*)(Ant + (size_t)kd * NN);
    const float4 t0 = at[0], t1 = at[1], t2 = at[2], t3 = at[3];
    An2[0]=v2(t0.x,t0.y); An2[1]=v2(t0.z,t0.w);
    An2[2]=v2(t1.x,t1.y); An2[3]=v2(t1.z,t1.w);
    An2[4]=v2(t2.x,t2.y); An2[5]=v2(t2.z,t2.w);
    An2[6]=v2(t3.x,t3.y); An2[7]=v2(t3.z,t3.w);
  }
  const float w0 = dtw[kd*6+0], w1 = dtw[kd*6+1], w2 = dtw[kd*6+2],
              w3 = dtw[kd*6+3], w4 = dtw[kd*6+4], w5 = dtw[kd*6+5];
  const float bias = dtb[kd];
  const ushort* __restrict__ up = (const ushort*)xt + (size_t)b * LL * DD + d;
  const float* __restrict__ dtrp = dtr + (size_t)bk * LL * 8;   // uniform rows
  __hip_bfloat16* __restrict__ yp = ys + (size_t)bk * LL * DD + d;

  v2f h2[8];
  const __hip_bfloat16* __restrict__ hp = hin + (((size_t)bk * NCH + c) * DD + d) * NN;
#pragma unroll
  for (int j = 0; j < 8; ++j)
    h2[j] = v2(__bfloat162float(hp[2*j]), __bfloat162float(hp[2*j+1]));

  uint ucur[8], unext[8] = {0,0,0,0,0,0,0,0};
#pragma unroll
  for (int i = 0; i < 8; ++i)
    ucur[i] = up[(size_t)urow(l0 + i, rev, trans) * DD];

  // depth-1 prefetch of the dtr pair (R17)
  float4 r0c = *(const float4*)(dtrp + (size_t)l0 * 8);
  float2 r1c = *(const float2*)(dtrp + (size_t)l0 * 8 + 4);

  asm volatile("s_waitcnt vmcnt(0)" ::: "memory");   // staged LDS + group-0 u ready

  for (int g = 0; g < 4; ++g) {
    if (g < 3) {
#pragma unroll
      for (int i = 0; i < 8; ++i)
        unext[i] = up[(size_t)urow(l0 + 8 * g + 8 + i, rev, trans) * DD];
    }
#pragma unroll
    for (int ii = 0; ii < 8; ++ii) {
      const int i = 8 * g + ii;
      const int l = l0 + i;
      const int lp = (i + 1 < LC) ? (l + 1) : l;   // next step's dtr row (clamped)
      const float4 r0n = *(const float4*)(dtrp + (size_t)lp * 8);
      const float2 r1n = *(const float2*)(dtrp + (size_t)lp * 8 + 4);
      const int rowc = urow(l, rev, trans);
      const float uc = __uint_as_float(ucur[ii] << 16);
      const float4 B0 = *(const float4*)(sB + i * 16);
      const float4 B1 = *(const float4*)(sB + i * 16 + 4);
      const float4 B2 = *(const float4*)(sB + i * 16 + 8);
      const float4 B3 = *(const float4*)(sB + i * 16 + 12);
      const float4 C0 = *(const float4*)(sC + i * 16);
      const float4 C1 = *(const float4*)(sC + i * 16 + 4);
      const float4 C2 = *(const float4*)(sC + i * 16 + 8);
      const float4 C3 = *(const float4*)(sC + i * 16 + 12);
      float v = bias + r0c.x*w0 + r0c.y*w1 + r0c.z*w2 + r0c.w*w3 + r1c.x*w4 + r1c.y*w5;
      const float sp = (v > 20.f) ? v : __logf(1.f + __expf(v));
      const float dbu = sp * uc;
      const v2f sp2  = v2(sp, sp);
      const v2f dbu2 = v2(dbu, dbu);
      const v2f Bv[8] = { v2(B0.x,B0.y), v2(B0.z,B0.w), v2(B1.x,B1.y), v2(B1.z,B1.w),
                          v2(B2.x,B2.y), v2(B2.z,B2.w), v2(B3.x,B3.y), v2(B3.z,B3.w) };
      const v2f Cv[8] = { v2(C0.x,C0.y), v2(C0.z,C0.w), v2(C1.x,C1.y), v2(C1.z,C1.w),
                          v2(C2.x,C2.y), v2(C2.z,C2.w), v2(C3.x,C3.y), v2(C3.z,C3.w) };
      v2f ya = v2(0.f, 0.f), yb = v2(0.f, 0.f), yc = v2(0.f, 0.f), yd = v2(0.f, 0.f);
#pragma unroll
      for (int j = 0; j < 8; ++j) {
        const v2f a = sp2 * An2[j];
        v2f e; e.x = fexp2(a.x); e.y = fexp2(a.y);
        h2[j] = __builtin_elementwise_fma(h2[j], e, dbu2 * Bv[j]);
        v2f& yacc = (j < 2) ? ya : (j < 4) ? yb : (j < 6) ? yc : yd;
        yacc = __builtin_elementwise_fma(h2[j], Cv[j], yacc);
      }
      const v2f ysum = (ya + yb) + (yc + yd);
      yp[(size_t)rowc * DD] = __float2bfloat16(ysum.x + ysum.y);
      r0c = r0n; r1c = r1n;
    }
#pragma unroll
    for (int i = 0; i < 8; ++i) ucur[i] = unext[i];
  }
}

// ---------------------------------------------------------------------------
// K6: merge + D-skip + LayerNorm(192) + channel-last store (unchanged).
// ---------------------------------------------------------------------------
__global__ __launch_bounds__(64) void k_merge(
    const __hip_bfloat16* __restrict__ ys,
    const __hip_bfloat16* __restrict__ xh, const __hip_bfloat16* __restrict__ xl,
    const float* __restrict__ Ds, const float* __restrict__ nw,
    const float* __restrict__ nb, float* __restrict__ out)
{
  const int lane = threadIdx.x;
  const int b = blockIdx.y;
  const int q0 = blockIdx.x * 8;

  float Dsum[3], nwv[3], nbv[3];
#pragma unroll
  for (int i = 0; i < 3; ++i) {
    int d = lane + 64 * i;
    Dsum[i] = Ds[d] + Ds[DD + d] + Ds[2 * DD + d] + Ds[3 * DD + d];
    nwv[i] = nw[d];
    nbv[i] = nb[d];
  }
  const __hip_bfloat16* __restrict__ ysb = ys + (size_t)b * 4 * LL * DD;
  const __hip_bfloat16* __restrict__ xhb = xh + (size_t)b * LL * DD;
  const __hip_bfloat16* __restrict__ xlb = xl + (size_t)b * LL * DD;
  float* __restrict__ ob = out + (size_t)b * LL * DD;

  float v[8][3];
#pragma unroll
  for (int j = 0; j < 8; ++j) {
    const int pos = q0 + j;
#pragma unroll
    for (int i = 0; i < 3; ++i) {
      const int d = lane + 64 * i;
      const size_t idx = (size_t)pos * DD + d;
      float s = __bfloat162float(ysb[idx])
              + __bfloat162float(ysb[(size_t)LL * DD + idx])
              + __bfloat162float(ysb[(size_t)2 * LL * DD + idx])
              + __bfloat162float(ysb[(size_t)3 * LL * DD + idx]);
      const float xv = __bfloat162float(xhb[idx]) + __bfloat162float(xlb[idx]);
      v[j][i] = s + xv * Dsum[i];
    }
  }
#pragma unroll
  for (int j = 0; j < 8; ++j) {
    float s1 = v[j][0] + v[j][1] + v[j][2];
    float s2 = v[j][0]*v[j][0] + v[j][1]*v[j][1] + v[j][2]*v[j][2];
#pragma unroll
    for (int m = 1; m < 64; m <<= 1) {
      s1 += __shfl_xor(s1, m);
      s2 += __shfl_xor(s2, m);
    }
    const float mu  = s1 * (1.f / 192.f);
    const float var = s2 * (1.f / 192.f) - mu * mu;
    const float rs  = rsqrtf(var + 1e-5f);
    const int pos = q0 + j;
#pragma unroll
    for (int i = 0; i < 3; ++i) {
      ob[(size_t)pos * DD + lane + 64 * i] = (v[j][i] - mu) * rs * nwv[i] + nbv[i];
    }
  }
}

// ---------------------------------------------------------------------------
// Workspace (fp32 slots), total 30,458,240 slots = 121.8 MB (unchanged):
//   dtr [32][4096][8]    fp32 @ 0           (1,048,576)
//   Bs  [32][4096][16]   fp32 @ 1,048,576   (2,097,152)
//   Cs  [32][4096][16]   fp32 @ 3,145,728   (2,097,152)
//   xh  [8][4096][192]   bf16 @ 5,242,880   (3,145,728 slots)
//   ys  [32][4096][192]  bf16 @ 8,388,608   (12,582,912 slots)
//     q  [32][128][192][16] bf16 @ 11,534,336 (aliases ys; dead after k_comb)
//   P/hin [32][128][192][16] bf16 @ 20,971,520 (6,291,456 slots)
//   Whi [192][192]       bf16 @ 27,262,976  (18,432 slots)
//   Wlo [192][192]       bf16 @ 27,281,408  (18,432 slots)
//   xl  [8][4096][192]   bf16 @ 27,299,840  (3,145,728 slots)
//   Ant [768][16]        fp32 @ 30,445,568  (12,288 slots)
// ---------------------------------------------------------------------------
extern "C" void kernel_launch(void* const* d_in, const int* in_sizes, int n_in,
                              void* d_out, int out_size, void* d_ws, size_t ws_size,
                              hipStream_t stream)
{
  (void)in_sizes; (void)n_in; (void)out_size; (void)ws_size;
  const float* x    = (const float*)d_in[0];
  const float* Wp   = (const float*)d_in[1];
  const float* dtw  = (const float*)d_in[2];
  const float* dtb  = (const float*)d_in[3];
  const float* Alog = (const float*)d_in[4];
  const float* Ds   = (const float*)d_in[5];
  const float* nw   = (const float*)d_in[6];
  const float* nb   = (const float*)d_in[7];
  float* out = (float*)d_out;
  float* ws  = (float*)d_ws;

  float* dtrw = ws;
  float* Bsv  = ws + 1048576;
  float* Csv  = ws + 3145728;
  __hip_bfloat16* xh  = (__hip_bfloat16*)(ws + 5242880);
  __hip_bfloat16* ysv = (__hip_bfloat16*)(ws + 8388608);
  __hip_bfloat16* qv  = (__hip_bfloat16*)(ws + 11534336);   // alias (dead early)
  __hip_bfloat16* Pv  = (__hip_bfloat16*)(ws + 20971520);
  __hip_bfloat16* Whi = (__hip_bfloat16*)(ws + 27262976);
  __hip_bfloat16* Wlo = (__hip_bfloat16*)(ws + 27281408);
  __hip_bfloat16* xlv = (__hip_bfloat16*)(ws + 27299840);
  float* Ant          = ws + 30445568;

  k_wprep  <<<192, 192, 0, stream>>>(Wp, Whi, Wlo);
  k_an     <<<48, 256, 0, stream>>>(Alog, Ant);
  k_xt     <<<dim3(64, 3, 8), 256, 0, stream>>>(x, xh, xlv);
  k_mfproj <<<dim3(256, 8), 192, 0, stream>>>(xh, xlv, Whi, Wlo, dtrw, Bsv, Csv);
  k_partial<<<dim3(32, NCH, 3), 64, 0, stream>>>(dtrw, Bsv, xh, Ant, dtw, dtb, Pv, qv);
  k_comb   <<<384, 256, 0, stream>>>(Pv, qv);
  k_scanc  <<<dim3(32, NCH, 3), 64, 0, stream>>>(dtrw, Bsv, Csv, xh, Ant, dtw, dtb, Pv, ysv);
  k_merge  <<<dim3(512, 8), 64, 0, stream>>>(ysv, xh, xlv, Ds, nw, nb, out);
}

// Round 9
// 323.398 us; speedup vs baseline: 1.3561x; 1.0017x over previous
//
#include <hip/hip_runtime.h>
#include <hip/hip_bf16.h>

#define LL 4096
#define DD 192
#define NN 16
#define NCH 128     // chunks for the 2-pass scan
#define LC  32      // steps per chunk = LL/NCH

typedef float v2f __attribute__((ext_vector_type(2)));
typedef float f32x4 __attribute__((ext_vector_type(4)));
typedef short bf16x8 __attribute__((ext_vector_type(8)));   // 8 bf16 in 4 VGPRs

__device__ __forceinline__ v2f v2(float a, float b) { v2f r; r.x = a; r.y = b; return r; }
__device__ __forceinline__ float fexp2(float x) { return __builtin_amdgcn_exp2f(x); }

// ---------------------------------------------------------------------------
// SCAN-KERNEL LEDGER (k_scanc dur):
//   R11 3wave noLDS 54%occ: 99.3 | R12 LDS 33%: 97.6 | R15: 100.6 |
//   R16 poly (+VALU): 164.2 | R17 dtr-prefetch: 100.1 | R18 (64,6): SPILL |
//   R19 1-wave (64,4): 97.9.
// CONCLUSIONS:
//  * Duration responds 1:1 to instruction count (R16) and to NOTHING else:
//    occupancy 33-54%, LDS vs global operands, prefetch depth, wave
//    geometry all null. VALUBusy pinned ~73%. Only lever left: fewer ops.
//  * SPILL RULE: min-waves>=6 in __launch_bounds__ forces the <=64-VGPR bin
//    -> this body spills (VGPR reads 40, FETCH+WRITE explode). Use 4.
//  * Spill watch every round: WRITE == 49152 KB exactly, VGPR ~56-70.
// R20: instruction shave -- drop useless R17 dtr prefetch; linearize row
// indices (rbase + i*rstep; R13 math, correctness proven by R13/R14 absmax).
// ---------------------------------------------------------------------------

// async global->LDS, 16 B per lane, dest = uniform base + lane*16 (HW rule).
#define GLDS16(gp, lp) __builtin_amdgcn_global_load_lds(                      \
    (const __attribute__((address_space(1))) void*)(gp),                      \
    (__attribute__((address_space(3))) void*)(lp), 16, 0, 0)

// ---------------------------------------------------------------------------
// K0: weight repack for the MFMA projection (unchanged).
// ---------------------------------------------------------------------------
__global__ __launch_bounds__(192) void k_wprep(
    const float* __restrict__ Wp, __hip_bfloat16* __restrict__ Whi,
    __hip_bfloat16* __restrict__ Wlo)
{
  const int d = threadIdx.x;
  const int r = blockIdx.x;
  const int k = r / 48, cc = r % 48;
  float v = 0.f;
  if      (cc < 6)               v = Wp[((size_t)k * 38 + cc) * DD + d];
  else if (cc >= 8  && cc < 24)  v = Wp[((size_t)k * 38 + 6  + (cc - 8))  * DD + d];
  else if (cc >= 24 && cc < 40)  v = Wp[((size_t)k * 38 + 22 + (cc - 24)) * DD + d];
  const __hip_bfloat16 hi = __float2bfloat16(v);
  Whi[(size_t)r * DD + d] = hi;
  Wlo[(size_t)r * DD + d] = __float2bfloat16(v - __bfloat162float(hi));
}

// ---------------------------------------------------------------------------
// K0b: A-table precompute. Ant[kd][n] = -exp(Alog)*log2e, fp32 [768][16].
// ---------------------------------------------------------------------------
__global__ __launch_bounds__(256) void k_an(
    const float* __restrict__ Alog, float* __restrict__ Ant)
{
  const int i = blockIdx.x * 256 + threadIdx.x;   // 12288 total
  Ant[i] = -__expf(Alog[i]) * 1.4426950408889634f;
}

// ---------------------------------------------------------------------------
// K2: tiled transpose x[b,d,p] -> xh (bf16 hi) + xl (residual) (unchanged).
// ---------------------------------------------------------------------------
__global__ __launch_bounds__(256) void k_xt(
    const float* __restrict__ x, __hip_bfloat16* __restrict__ xh,
    __hip_bfloat16* __restrict__ xl)
{
  __shared__ float tile[64][65];
  const int b = blockIdx.z, d0 = blockIdx.y * 64, p0 = blockIdx.x * 64;
  const int tx = threadIdx.x & 63, ty = threadIdx.x >> 6;
#pragma unroll
  for (int r = ty; r < 64; r += 4)
    tile[r][tx] = x[((size_t)b * DD + d0 + r) * LL + p0 + tx];
  __syncthreads();
#pragma unroll
  for (int pr = ty; pr < 64; pr += 4) {
    const float vv = tile[tx][pr];
    const __hip_bfloat16 hi = __float2bfloat16(vv);
    const size_t idx = ((size_t)b * LL + p0 + pr) * DD + d0 + tx;
    xh[idx] = hi;
    xl[idx] = __float2bfloat16(vv - __bfloat162float(hi));
  }
}

// ---------------------------------------------------------------------------
// K1: MFMA projection (unchanged).
// ---------------------------------------------------------------------------
__global__ __launch_bounds__(192) void k_mfproj(
    const __hip_bfloat16* __restrict__ xh, const __hip_bfloat16* __restrict__ xl,
    const __hip_bfloat16* __restrict__ Whi, const __hip_bfloat16* __restrict__ Wlo,
    float* __restrict__ dtr, float* __restrict__ Bsv, float* __restrict__ Csv)
{
  const int tid  = threadIdx.x;
  const int w    = tid >> 6;          // wave 0..2
  const int lane = tid & 63;
  const int n    = lane & 15;
  const int quad = lane >> 4;
  const int p0   = blockIdx.x * 16;
  const int b    = blockIdx.y;
  const int p    = p0 + n;

  const short* __restrict__ xhp = (const short*)xh + ((size_t)b * LL + p) * DD + quad * 8;
  const short* __restrict__ xlp = (const short*)xl + ((size_t)b * LL + p) * DD + quad * 8;
  const short* __restrict__ whp = (const short*)Whi + ((size_t)(w * 4) * 16 + n) * DD + quad * 8;
  const short* __restrict__ wlp = (const short*)Wlo + ((size_t)(w * 4) * 16 + n) * DD + quad * 8;

  f32x4 acc[4];
#pragma unroll
  for (int m = 0; m < 4; ++m) acc[m] = (f32x4){0.f, 0.f, 0.f, 0.f};

#pragma unroll
  for (int ks = 0; ks < 6; ++ks) {
    const bf16x8 bh = *(const bf16x8*)(xhp + ks * 32);
    const bf16x8 bl = *(const bf16x8*)(xlp + ks * 32);
#pragma unroll
    for (int m = 0; m < 4; ++m) {
      const bf16x8 ah = *(const bf16x8*)(whp + (size_t)m * 16 * DD + ks * 32);
      const bf16x8 al = *(const bf16x8*)(wlp + (size_t)m * 16 * DD + ks * 32);
      acc[m] = __builtin_amdgcn_mfma_f32_16x16x32_bf16(ah, bh, acc[m], 0, 0, 0);
      acc[m] = __builtin_amdgcn_mfma_f32_16x16x32_bf16(ah, bl, acc[m], 0, 0, 0);
      acc[m] = __builtin_amdgcn_mfma_f32_16x16x32_bf16(al, bh, acc[m], 0, 0, 0);
    }
  }

  const int sg = ((p & 63) << 6) | (p >> 6);     // sigma(p)
  int lsv[4] = { p, sg, LL - 1 - p, LL - 1 - sg };

#pragma unroll
  for (int m = 0; m < 4; ++m) {
    const int mt = w * 4 + m;
    const int k  = mt / 3;                        // direction
    const int t  = mt - k * 3;                    // tile within direction
    const int cc0 = t * 16 + quad * 4;            // packed channel of reg 0
    const size_t rowb = (size_t)(b * 4 + k) * LL + lsv[k];
    const float4 vv = make_float4(acc[m][0], acc[m][1], acc[m][2], acc[m][3]);
    if      (cc0 < 8)  *(float4*)(dtr + rowb * 8  + cc0)        = vv;
    else if (cc0 < 24) *(float4*)(Bsv + rowb * 16 + (cc0 - 8))  = vv;
    else if (cc0 < 40) *(float4*)(Csv + rowb * 16 + (cc0 - 24)) = vv;
  }
}

// u-row index for scan position l of direction k.
__device__ __forceinline__ int urow(int l, bool rev, bool trans) {
  const int rl = rev ? (LL - 1 - l) : l;
  return trans ? (((rl & 63) << 6) | (rl >> 6)) : rl;
}

// ---------------------------------------------------------------------------
// K3 (pass A): per-chunk scan summaries. R20: 1-wave (64,4) [R19-clean] +
// linear row indexing (rbase + i*rstep; exact within a chunk since l0 is a
// multiple of 32) + direct per-step dtr loads (R17 prefetch reverted).
// ---------------------------------------------------------------------------
__global__ __launch_bounds__(64, 4) void k_partial(
    const float* __restrict__ dtr, const float* __restrict__ Bsv,
    const __hip_bfloat16* __restrict__ xt, const float* __restrict__ Ant,
    const float* __restrict__ dtw, const float* __restrict__ dtb,
    __hip_bfloat16* __restrict__ Pv, __hip_bfloat16* __restrict__ qv)
{
  __shared__ __align__(16) float smem[LC * 16];   // B, one wave's copy
  const int lane = threadIdx.x;
  const int d  = blockIdx.z * 64 + lane;
  const int bk = blockIdx.x;
  const int c  = blockIdx.y;
  const int k = bk & 3, b = bk >> 2;
  const int kd = k * DD + d;
  const bool rev = (k >= 2), trans = (k & 1);
  const int l0 = c * LC;

  float* sB = smem;    // [LC][16]
  {
    const float* gB = Bsv + ((size_t)bk * LL + l0) * NN;   // 2048 B
    GLDS16(gB + lane * 4, sB);
    GLDS16(gB + 256 + lane * 4, sB + 256);
  }

  v2f An2[8];
  {
    const float4* __restrict__ at = (const float4*)(Ant + (size_t)kd * NN);
    const float4 t0 = at[0], t1 = at[1], t2 = at[2], t3 = at[3];
    An2[0]=v2(t0.x,t0.y); An2[1]=v2(t0.z,t0.w);
    An2[2]=v2(t1.x,t1.y); An2[3]=v2(t1.z,t1.w);
    An2[4]=v2(t2.x,t2.y); An2[5]=v2(t2.z,t2.w);
    An2[6]=v2(t3.x,t3.y); An2[7]=v2(t3.z,t3.w);
  }
  const float w0 = dtw[kd*6+0], w1 = dtw[kd*6+1], w2 = dtw[kd*6+2],
              w3 = dtw[kd*6+3], w4 = dtw[kd*6+4], w5 = dtw[kd*6+5];
  const float bias = dtb[kd];
  const ushort* __restrict__ up = (const ushort*)xt + (size_t)b * LL * DD + d;
  const float* __restrict__ dtrp = dtr + (size_t)bk * LL * 8;   // uniform rows

  // linear row walk within the chunk (R13 math, proven correct)
  const int rbase = urow(l0, rev, trans);
  const int rstep = trans ? (rev ? -64 : 64) : (rev ? -1 : 1);

  // 8-deep rolling register prefetch of the per-thread u stream.
  uint ucur[8], unext[8] = {0,0,0,0,0,0,0,0};
#pragma unroll
  for (int i = 0; i < 8; ++i)
    ucur[i] = up[(size_t)(rbase + i * rstep) * DD];

  asm volatile("s_waitcnt vmcnt(0)" ::: "memory");   // staged LDS + group-0 u ready

  float spsum = 0.f;
  v2f q2[8];
#pragma unroll
  for (int j = 0; j < 8; ++j) q2[j] = v2(0.f, 0.f);

  for (int g = 0; g < 4; ++g) {
    if (g < 3) {
#pragma unroll
      for (int i = 0; i < 8; ++i)
        unext[i] = up[(size_t)(rbase + (8 * g + 8 + i) * rstep) * DD];
    }
#pragma unroll
    for (int ii = 0; ii < 8; ++ii) {
      const int i = 8 * g + ii;
      const int l = l0 + i;
      const float uc = __uint_as_float(ucur[ii] << 16);
      const float4 r0 = *(const float4*)(dtrp + (size_t)l * 8);
      const float2 r1 = *(const float2*)(dtrp + (size_t)l * 8 + 4);
      const float4 B0 = *(const float4*)(sB + i * 16);
      const float4 B1 = *(const float4*)(sB + i * 16 + 4);
      const float4 B2 = *(const float4*)(sB + i * 16 + 8);
      const float4 B3 = *(const float4*)(sB + i * 16 + 12);
      float v = bias + r0.x*w0 + r0.y*w1 + r0.z*w2 + r0.w*w3 + r1.x*w4 + r1.y*w5;
      const float sp = (v > 20.f) ? v : __logf(1.f + __expf(v));
      const float dbu = sp * uc;
      spsum += sp;
      const v2f sp2  = v2(sp, sp);
      const v2f dbu2 = v2(dbu, dbu);
      const v2f Bv[8] = { v2(B0.x,B0.y), v2(B0.z,B0.w), v2(B1.x,B1.y), v2(B1.z,B1.w),
                          v2(B2.x,B2.y), v2(B2.z,B2.w), v2(B3.x,B3.y), v2(B3.z,B3.w) };
#pragma unroll
      for (int j = 0; j < 8; ++j) {
        const v2f a = sp2 * An2[j];                 // v_pk_mul
        v2f e; e.x = fexp2(a.x); e.y = fexp2(a.y);
        q2[j] = __builtin_elementwise_fma(q2[j], e, dbu2 * Bv[j]);  // pk_mul+pk_fma
      }
    }
#pragma unroll
    for (int i = 0; i < 8; ++i) ucur[i] = unext[i];
  }

  __hip_bfloat16* __restrict__ Pp = Pv + (((size_t)bk * NCH + c) * DD + d) * NN;
  __hip_bfloat16* __restrict__ qp = qv + (((size_t)bk * NCH + c) * DD + d) * NN;
#pragma unroll
  for (int j = 0; j < 8; ++j) {
    Pp[2*j]   = __float2bfloat16(fexp2(An2[j].x * spsum));
    Pp[2*j+1] = __float2bfloat16(fexp2(An2[j].y * spsum));
    qp[2*j]   = __float2bfloat16(q2[j].x);
    qp[2*j+1] = __float2bfloat16(q2[j].y);
  }
}

// ---------------------------------------------------------------------------
// K4 (pass B): combine chunk summaries; h_in[c] overwrites P[c] in place.
// ---------------------------------------------------------------------------
__global__ __launch_bounds__(256) void k_comb(
    __hip_bfloat16* __restrict__ Pv, const __hip_bfloat16* __restrict__ qv)
{
  const int idx = blockIdx.x * 256 + threadIdx.x;
  const int dn = idx % (DD * NN);
  const int bk = idx / (DD * NN);
  const size_t base = (size_t)bk * NCH * DD * NN + dn;
  float h = 0.f;
  for (int c = 0; c < NCH; ++c) {
    const size_t a = base + (size_t)c * DD * NN;
    const float Pc = __bfloat162float(Pv[a]);
    const float qc = __bfloat162float(qv[a]);
    Pv[a] = __float2bfloat16(h);          // hin[c] = h (pre-chunk state)
    h = fmaf(Pc, h, qc);
  }
}

// ---------------------------------------------------------------------------
// K5 (pass C): real scan per chunk seeded with h_in. R20: linear rows +
// direct dtr loads, 1-wave (64,4).
// ---------------------------------------------------------------------------
__global__ __launch_bounds__(64, 4) void k_scanc(
    const float* __restrict__ dtr, const float* __restrict__ Bsv,
    const float* __restrict__ Csv, const __hip_bfloat16* __restrict__ xt,
    const float* __restrict__ Ant,
    const float* __restrict__ dtw, const float* __restrict__ dtb,
    const __hip_bfloat16* __restrict__ hin, __hip_bfloat16* __restrict__ ys)
{
  __shared__ __align__(16) float smem[LC * 32];   // B + C, one wave's copy
  const int lane = threadIdx.x;
  const int d  = blockIdx.z * 64 + lane;
  const int bk = blockIdx.x;
  const int c  = blockIdx.y;
  const int k = bk & 3, b = bk >> 2;
  const int kd = k * DD + d;
  const bool rev = (k >= 2), trans = (k & 1);
  const int l0 = c * LC;

  float* sB = smem;             // [LC][16]
  float* sC = smem + LC * 16;   // [LC][16]
  {
    const float* gB = Bsv + ((size_t)bk * LL + l0) * NN;   // 2048 B
    const float* gC = Csv + ((size_t)bk * LL + l0) * NN;   // 2048 B
    GLDS16(gB + lane * 4, sB);
    GLDS16(gB + 256 + lane * 4, sB + 256);
    GLDS16(gC + lane * 4, sC);
    GLDS16(gC + 256 + lane * 4, sC + 256);
  }

  v2f An2[8];
  {
    const float4* __restrict__ at = (const float4*)(Ant + (size_t)kd * NN);
    const float4 t0 = at[0], t1 = at[1], t2 = at[2], t3 = at[3];
    An2[0]=v2(t0.x,t0.y); An2[1]=v2(t0.z,t0.w);
    An2[2]=v2(t1.x,t1.y); An2[3]=v2(t1.z,t1.w);
    An2[4]=v2(t2.x,t2.y); An2[5]=v2(t2.z,t2.w);
    An2[6]=v2(t3.x,t3.y); An2[7]=v2(t3.z,t3.w);
  }
  const float w0 = dtw[kd*6+0], w1 = dtw[kd*6+1], w2 = dtw[kd*6+2],
              w3 = dtw[kd*6+3], w4 = dtw[kd*6+4], w5 = dtw[kd*6+5];
  const float bias = dtb[kd];
  const ushort* __restrict__ up = (const ushort*)xt + (size_t)b * LL * DD + d;
  const float* __restrict__ dtrp = dtr + (size_t)bk * LL * 8;   // uniform rows
  __hip_bfloat16* __restrict__ yp = ys + (size_t)bk * LL * DD + d;

  v2f h2[8];
  const __hip_bfloat16* __restrict__ hp = hin + (((size_t)bk * NCH + c) * DD + d) * NN;
#pragma unroll
  for (int j = 0; j < 8; ++j)
    h2[j] = v2(__bfloat162float(hp[2*j]), __bfloat162float(hp[2*j+1]));

  // linear row walk within the chunk (R13 math, proven correct)
  const int rbase = urow(l0, rev, trans);
  const int rstep = trans ? (rev ? -64 : 64) : (rev ? -1 : 1);

  uint ucur[8], unext[8] = {0,0,0,0,0,0,0,0};
#pragma unroll
  for (int i = 0; i < 8; ++i)
    ucur[i] = up[(size_t)(rbase + i * rstep) * DD];

  asm volatile("s_waitcnt vmcnt(0)" ::: "memory");   // staged LDS + group-0 u ready

  for (int g = 0; g < 4; ++g) {
    if (g < 3) {
#pragma unroll
      for (int i = 0; i < 8; ++i)
        unext[i] = up[(size_t)(rbase + (8 * g + 8 + i) * rstep) * DD];
    }
#pragma unroll
    for (int ii = 0; ii < 8; ++ii) {
      const int i = 8 * g + ii;
      const int l = l0 + i;
      const int rowc = rbase + i * rstep;
      const float uc = __uint_as_float(ucur[ii] << 16);
      const float4 r0 = *(const float4*)(dtrp + (size_t)l * 8);
      const float2 r1 = *(const float2*)(dtrp + (size_t)l * 8 + 4);
      const float4 B0 = *(const float4*)(sB + i * 16);
      const float4 B1 = *(const float4*)(sB + i * 16 + 4);
      const float4 B2 = *(const float4*)(sB + i * 16 + 8);
      const float4 B3 = *(const float4*)(sB + i * 16 + 12);
      const float4 C0 = *(const float4*)(sC + i * 16);
      const float4 C1 = *(const float4*)(sC + i * 16 + 4);
      const float4 C2 = *(const float4*)(sC + i * 16 + 8);
      const float4 C3 = *(const float4*)(sC + i * 16 + 12);
      float v = bias + r0.x*w0 + r0.y*w1 + r0.z*w2 + r0.w*w3 + r1.x*w4 + r1.y*w5;
      const float sp = (v > 20.f) ? v : __logf(1.f + __expf(v));
      const float dbu = sp * uc;
      const v2f sp2  = v2(sp, sp);
      const v2f dbu2 = v2(dbu, dbu);
      const v2f Bv[8] = { v2(B0.x,B0.y), v2(B0.z,B0.w), v2(B1.x,B1.y), v2(B1.z,B1.w),
                          v2(B2.x,B2.y), v2(B2.z,B2.w), v2(B3.x,B3.y), v2(B3.z,B3.w) };
      const v2f Cv[8] = { v2(C0.x,C0.y), v2(C0.z,C0.w), v2(C1.x,C1.y), v2(C1.z,C1.w),
                          v2(C2.x,C2.y), v2(C2.z,C2.w), v2(C3.x,C3.y), v2(C3.z,C3.w) };
      v2f ya = v2(0.f, 0.f), yb = v2(0.f, 0.f), yc = v2(0.f, 0.f), yd = v2(0.f, 0.f);
#pragma unroll
      for (int j = 0; j < 8; ++j) {
        const v2f a = sp2 * An2[j];
        v2f e; e.x = fexp2(a.x); e.y = fexp2(a.y);
        h2[j] = __builtin_elementwise_fma(h2[j], e, dbu2 * Bv[j]);
        v2f& yacc = (j < 2) ? ya : (j < 4) ? yb : (j < 6) ? yc : yd;
        yacc = __builtin_elementwise_fma(h2[j], Cv[j], yacc);
      }
      const v2f ysum = (ya + yb) + (yc + yd);
      yp[(size_t)rowc * DD] = __float2bfloat16(ysum.x + ysum.y);
    }
#pragma unroll
    for (int i = 0; i < 8; ++i) ucur[i] = unext[i];
  }
}

// ---------------------------------------------------------------------------
// K6: merge + D-skip + LayerNorm(192) + channel-last store (unchanged).
// ---------------------------------------------------------------------------
__global__ __launch_bounds__(64) void k_merge(
    const __hip_bfloat16* __restrict__ ys,
    const __hip_bfloat16* __restrict__ xh, const __hip_bfloat16* __restrict__ xl,
    const float* __restrict__ Ds, const float* __restrict__ nw,
    const float* __restrict__ nb, float* __restrict__ out)
{
  const int lane = threadIdx.x;
  const int b = blockIdx.y;
  const int q0 = blockIdx.x * 8;

  float Dsum[3], nwv[3], nbv[3];
#pragma unroll
  for (int i = 0; i < 3; ++i) {
    int d = lane + 64 * i;
    Dsum[i] = Ds[d] + Ds[DD + d] + Ds[2 * DD + d] + Ds[3 * DD + d];
    nwv[i] = nw[d];
    nbv[i] = nb[d];
  }
  const __hip_bfloat16* __restrict__ ysb = ys + (size_t)b * 4 * LL * DD;
  const __hip_bfloat16* __restrict__ xhb = xh + (size_t)b * LL * DD;
  const __hip_bfloat16* __restrict__ xlb = xl + (size_t)b * LL * DD;
  float* __restrict__ ob = out + (size_t)b * LL * DD;

  float v[8][3];
#pragma unroll
  for (int j = 0; j < 8; ++j) {
    const int pos = q0 + j;
#pragma unroll
    for (int i = 0; i < 3; ++i) {
      const int d = lane + 64 * i;
      const size_t idx = (size_t)pos * DD + d;
      float s = __bfloat162float(ysb[idx])
              + __bfloat162float(ysb[(size_t)LL * DD + idx])
              + __bfloat162float(ysb[(size_t)2 * LL * DD + idx])
              + __bfloat162float(ysb[(size_t)3 * LL * DD + idx]);
      const float xv = __bfloat162float(xhb[idx]) + __bfloat162float(xlb[idx]);
      v[j][i] = s + xv * Dsum[i];
    }
  }
#pragma unroll
  for (int j = 0; j < 8; ++j) {
    float s1 = v[j][0] + v[j][1] + v[j][2];
    float s2 = v[j][0]*v[j][0] + v[j][1]*v[j][1] + v[j][2]*v[j][2];
#pragma unroll
    for (int m = 1; m < 64; m <<= 1) {
      s1 += __shfl_xor(s1, m);
      s2 += __shfl_xor(s2, m);
    }
    const float mu  = s1 * (1.f / 192.f);
    const float var = s2 * (1.f / 192.f) - mu * mu;
    const float rs  = rsqrtf(var + 1e-5f);
    const int pos = q0 + j;
#pragma unroll
    for (int i = 0; i < 3; ++i) {
      ob[(size_t)pos * DD + lane + 64 * i] = (v[j][i] - mu) * rs * nwv[i] + nbv[i];
    }
  }
}

// ---------------------------------------------------------------------------
// Workspace (fp32 slots), total 30,458,240 slots = 121.8 MB (unchanged):
//   dtr [32][4096][8]    fp32 @ 0           (1,048,576)
//   Bs  [32][4096][16]   fp32 @ 1,048,576   (2,097,152)
//   Cs  [32][4096][16]   fp32 @ 3,145,728   (2,097,152)
//   xh  [8][4096][192]   bf16 @ 5,242,880   (3,145,728 slots)
//   ys  [32][4096][192]  bf16 @ 8,388,608   (12,582,912 slots)
//     q  [32][128][192][16] bf16 @ 11,534,336 (aliases ys; dead after k_comb)
//   P/hin [32][128][192][16] bf16 @ 20,971,520 (6,291,456 slots)
//   Whi [192][192]       bf16 @ 27,262,976  (18,432 slots)
//   Wlo [192][192]       bf16 @ 27,281,408  (18,432 slots)
//   xl  [8][4096][192]   bf16 @ 27,299,840  (3,145,728 slots)
//   Ant [768][16]        fp32 @ 30,445,568  (12,288 slots)
// ---------------------------------------------------------------------------
extern "C" void kernel_launch(void* const* d_in, const int* in_sizes, int n_in,
                              void* d_out, int out_size, void* d_ws, size_t ws_size,
                              hipStream_t stream)
{
  (void)in_sizes; (void)n_in; (void)out_size; (void)ws_size;
  const float* x    = (const float*)d_in[0];
  const float* Wp   = (const float*)d_in[1];
  const float* dtw  = (const float*)d_in[2];
  const float* dtb  = (const float*)d_in[3];
  const float* Alog = (const float*)d_in[4];
  const float* Ds   = (const float*)d_in[5];
  const float* nw   = (const float*)d_in[6];
  const float* nb   = (const float*)d_in[7];
  float* out = (float*)d_out;
  float* ws  = (float*)d_ws;

  float* dtrw = ws;
  float* Bsv  = ws + 1048576;
  float* Csv  = ws + 3145728;
  __hip_bfloat16* xh  = (__hip_bfloat16*)(ws + 5242880);
  __hip_bfloat16* ysv = (__hip_bfloat16*)(ws + 8388608);
  __hip_bfloat16* qv  = (__hip_bfloat16*)(ws + 11534336);   // alias (dead early)
  __hip_bfloat16* Pv  = (__hip_bfloat16*)(ws + 20971520);
  __hip_bfloat16* Whi = (__hip_bfloat16*)(ws + 27262976);
  __hip_bfloat16* Wlo = (__hip_bfloat16*)(ws + 27281408);
  __hip_bfloat16* xlv = (__hip_bfloat16*)(ws + 27299840);
  float* Ant          = ws + 30445568;

  k_wprep  <<<192, 192, 0, stream>>>(Wp, Whi, Wlo);
  k_an     <<<48, 256, 0, stream>>>(Alog, Ant);
  k_xt     <<<dim3(64, 3, 8), 256, 0, stream>>>(x, xh, xlv);
  k_mfproj <<<dim3(256, 8), 192, 0, stream>>>(xh, xlv, Whi, Wlo, dtrw, Bsv, Csv);
  k_partial<<<dim3(32, NCH, 3), 64, 0, stream>>>(dtrw, Bsv, xh, Ant, dtw, dtb, Pv, qv);
  k_comb   <<<384, 256, 0, stream>>>(Pv, qv);
  k_scanc  <<<dim3(32, NCH, 3), 64, 0, stream>>>(dtrw, Bsv, Csv, xh, Ant, dtw, dtb, Pv, ysv);
  k_merge  <<<dim3(512, 8), 64, 0, stream>>>(ysv, xh, xlv, Ds, nw, nb, out);
}